// Round 16
// baseline (278.402 us; speedup 1.0000x reference)
//
#include <hip/hip_runtime.h>
#include <cstdint>
#include <cstddef>

typedef float f32x4 __attribute__((ext_vector_type(4)));
typedef short bf16x8 __attribute__((ext_vector_type(8)));
typedef short bf16x4 __attribute__((ext_vector_type(4)));
typedef unsigned int u32x4 __attribute__((ext_vector_type(4)));

#define LOG2E 1.4426950408889634f
#define K2E 0.12750102296293331f  /* (1/sqrt(128))*log2(e) */
#define MFMA_BF16 __builtin_amdgcn_mfma_f32_16x16x32_bf16

__device__ inline float bf2f(short s) {
  return (float)__builtin_bit_cast(__bf16, s);
}
__device__ inline short f2bf(float f) {
  return __builtin_bit_cast(short, (__bf16)f);
}
__device__ inline unsigned f2bfu(float f) {
  return (unsigned)__builtin_bit_cast(unsigned short, (__bf16)f);
}

__device__ inline void gload_lds16(const void* g, void* l) {
  __builtin_amdgcn_global_load_lds(
      (const __attribute__((address_space(1))) void*)g,
      (__attribute__((address_space(3))) void*)l, 16, 0, 0);
}

// ------- fused fp32->bf16: x (8.4M) then Wq|Wk|Wv|Wo (4x4.2M), one output --
__global__ __launch_bounds__(256) void cvt_all(const float* __restrict__ x,
                                               const float* __restrict__ w0,
                                               const float* __restrict__ w1,
                                               const float* __restrict__ w2,
                                               const float* __restrict__ w3,
                                               __bf16* __restrict__ out) {
  int i = (blockIdx.x * 256 + threadIdx.x) * 8;  // [0, 25165824)
  const float* s;
  int off;
  if (i < 8388608) {
    s = x; off = i;
  } else {
    int j = i - 8388608;
    int sel = j >> 22;  // block-uniform
    s = (sel == 0) ? w0 : (sel == 1) ? w1 : (sel == 2) ? w2 : w3;
    off = j & 4194303;
  }
  f32x4 a = *(const f32x4*)(s + off);
  f32x4 b = *(const f32x4*)(s + off + 4);
  bf16x8 r;
#pragma unroll
  for (int j = 0; j < 4; ++j) {
    r[j]     = f2bf(a[j]);
    r[j + 4] = f2bf(b[j]);
  }
  *(bf16x8*)(out + i) = r;
}

// ============ 128x256 2-phase GEMM: C = A * B^T (zero-tail grids) ============
// Triple-buffered A/B0/B1. Phase = [ds_reads; stage; counted-vmcnt; barrier;
// MFMA]. ROPE: fused rotary on the f32 acc in the epilogue (Q/K cols only;
// pair = adjacent lanes via shfl_xor(1)).
__device__ inline void stage_half(const __bf16* __restrict__ gbase, int K,
                                  int k0, char* ldsHalf, int wid, int lane) {
#pragma unroll
  for (int j = 0; j < 2; ++j) {
    int idx = (wid * 2 + j) * 64 + lane;
    int row = idx >> 3;
    int c16 = (idx & 7) ^ (row & 7);
    gload_lds16(gbase + (size_t)row * K + k0 + c16 * 8,
                ldsHalf + (wid * 2 + j) * 1024);
  }
}

__device__ inline bf16x8 lds_frag(const char* halfbase, int row, int ks, int g) {
  return *(const bf16x8*)(halfbase + row * 128 + ((((ks << 2) | g) ^ (row & 7)) << 4));
}

#define WAITV(n) asm volatile("s_waitcnt vmcnt(" #n ")" ::: "memory")

template <bool OUT_F32, bool ROPE>
__global__ __launch_bounds__(512, 1) void gemm128(const __bf16* __restrict__ A,
                                                  const __bf16* __restrict__ B,
                                                  void* __restrict__ Cv,
                                                  const float* __restrict__ fc,
                                                  const float* __restrict__ fs,
                                                  int M, int N, int K) {
  __shared__ __attribute__((aligned(128))) char lds[147456];
  const int tid = threadIdx.x, wid = tid >> 6, lane = tid & 63;
  const int g = lane >> 4, lc = lane & 15;
  const int wm = wid >> 2, wn = wid & 3;

  const int gx = gridDim.x;
  int nwg = gx * gridDim.y;
  int bid = blockIdx.y * gx + blockIdx.x;
  int cpx = nwg >> 3;
  int swz = (bid & 7) * cpx + (bid >> 3);
  const int bx = swz % gx, by = swz / gx;

  const __bf16* Ag = A + (size_t)(by * 128) * K;
  const __bf16* Bg = B + (size_t)(bx * 256) * K;
  const __bf16* Bg1 = Bg + 128 * (size_t)K;
  const int NT = K >> 6;

  f32x4 acc[2][4][2];
#pragma unroll
  for (int hb = 0; hb < 2; ++hb)
#pragma unroll
    for (int m = 0; m < 4; ++m)
#pragma unroll
      for (int n = 0; n < 2; ++n) acc[hb][m][n] = f32x4{0.f, 0.f, 0.f, 0.f};

  stage_half(Ag,  K, 0,  lds + 0,             wid, lane);
  stage_half(Bg,  K, 0,  lds + 49152,         wid, lane);
  stage_half(Bg1, K, 0,  lds + 98304,         wid, lane);
  stage_half(Ag,  K, 64, lds + 16384,         wid, lane);
  stage_half(Bg,  K, 64, lds + 49152 + 16384, wid, lane);
  stage_half(Bg1, K, 64, lds + 98304 + 16384, wid, lane);
  WAITV(8);
  __builtin_amdgcn_s_barrier();

  bf16x8 a[4][2], b0[2][2], b1[2][2];
  int sc = 0;

  for (int T = 0; T < NT; ++T) {
    char* As  = lds + sc * 16384;
    char* B0s = lds + 49152 + sc * 16384;
    char* B1s = lds + 98304 + sc * 16384;
    int s2 = sc + 2; if (s2 >= 3) s2 -= 3;
    char* As2  = lds + s2 * 16384;
    char* B0s2 = lds + 49152 + s2 * 16384;
    char* B1s2 = lds + 98304 + s2 * 16384;
    const int k2 = (T + 2) << 6;

    // ---- phase 1: C-half 0 ----
#pragma unroll
    for (int m = 0; m < 4; ++m)
#pragma unroll
      for (int ks = 0; ks < 2; ++ks)
        a[m][ks] = lds_frag(As, wm * 64 + m * 16 + lc, ks, g);
#pragma unroll
    for (int n = 0; n < 2; ++n)
#pragma unroll
      for (int ks = 0; ks < 2; ++ks)
        b0[n][ks] = lds_frag(B0s, wn * 32 + n * 16 + lc, ks, g);
    if (T + 2 < NT) {
      stage_half(Ag, K, k2, As2, wid, lane);
      stage_half(Bg, K, k2, B0s2, wid, lane);
      WAITV(10);
    } else if (T + 1 < NT) {
      WAITV(6);
    } else {
      WAITV(0);
    }
    __builtin_amdgcn_s_barrier();
    __builtin_amdgcn_s_setprio(1);
#pragma unroll
    for (int m = 0; m < 4; ++m)
#pragma unroll
      for (int n = 0; n < 2; ++n) {
        acc[0][m][n] = MFMA_BF16(a[m][0], b0[n][0], acc[0][m][n], 0, 0, 0);
        acc[0][m][n] = MFMA_BF16(a[m][1], b0[n][1], acc[0][m][n], 0, 0, 0);
      }
    __builtin_amdgcn_s_setprio(0);

    // ---- phase 2: C-half 1 ----
#pragma unroll
    for (int n = 0; n < 2; ++n)
#pragma unroll
      for (int ks = 0; ks < 2; ++ks)
        b1[n][ks] = lds_frag(B1s, wn * 32 + n * 16 + lc, ks, g);
    if (T + 2 < NT) {
      stage_half(Bg1, K, k2, B1s2, wid, lane);
      WAITV(8);
    } else if (T + 1 < NT) {
      WAITV(2);
    }
    __builtin_amdgcn_s_barrier();
    __builtin_amdgcn_s_setprio(1);
#pragma unroll
    for (int m = 0; m < 4; ++m)
#pragma unroll
      for (int n = 0; n < 2; ++n) {
        acc[1][m][n] = MFMA_BF16(a[m][0], b1[n][0], acc[1][m][n], 0, 0, 0);
        acc[1][m][n] = MFMA_BF16(a[m][1], b1[n][1], acc[1][m][n], 0, 0, 0);
      }
    __builtin_amdgcn_s_setprio(0);

    sc = (sc + 1 == 3) ? 0 : sc + 1;
  }

  // ---- fused RoPE on f32 acc (Q/K cols: bx < 16 covers cols < 4096) ----
  if (ROPE && bx < 16) {
#pragma unroll
    for (int m = 0; m < 4; ++m)
#pragma unroll
      for (int r = 0; r < 4; ++r) {
        int l = (by * 128 + wm * 64 + m * 16 + g * 4 + r) & 2047;
#pragma unroll
        for (int n = 0; n < 2; ++n) {
          int i0 = (wn * 32 + n * 16 + lc) >> 1;
          float c = fc[l * 64 + i0];
          float s = fs[l * 64 + i0];
#pragma unroll
          for (int hb = 0; hb < 2; ++hb) {
            float v = acc[hb][m][n][r];
            float pv = __shfl_xor(v, 1);
            acc[hb][m][n][r] = (lc & 1) ? (pv * s + v * c) : (v * c - pv * s);
          }
        }
      }
  }

  // epilogue
#pragma unroll
  for (int hb = 0; hb < 2; ++hb)
#pragma unroll
    for (int m = 0; m < 4; ++m)
#pragma unroll
      for (int n = 0; n < 2; ++n)
#pragma unroll
        for (int r = 0; r < 4; ++r) {
          int rr = by * 128 + wm * 64 + m * 16 + g * 4 + r;
          int cc = bx * 256 + hb * 128 + wn * 32 + n * 16 + lc;
          if (OUT_F32)
            ((float*)Cv)[(size_t)rr * N + cc] = acc[hb][m][n][r];
          else
            ((__bf16*)Cv)[(size_t)rr * N + cc] = (__bf16)acc[hb][m][n][r];
        }
}

// ---------------- V transpose: (b,l,h,d) -> (b,h,d,l) ----------------
__global__ void transpose_v(const __bf16* __restrict__ qkv, __bf16* __restrict__ vt) {
  __shared__ __bf16 tile[32][33];
  const int b = blockIdx.z;
  const int l0 = blockIdx.x * 32, c0 = blockIdx.y * 32;
  for (int i = threadIdx.y; i < 32; i += 8)
    tile[i][threadIdx.x] = qkv[(size_t)(b * 2048 + l0 + i) * 6144 + 4096 + c0 + threadIdx.x];
  __syncthreads();
  for (int i = threadIdx.y; i < 32; i += 8)
    vt[(size_t)b * 4194304 + (size_t)(c0 + i) * 2048 + l0 + threadIdx.x] = tile[threadIdx.x][i];
}

// ---------------- causal flash attention, uniform paired q-tiles ----------
// 32 q-tiles of 64 rows; block j: tile j (j+1 units) + tile 31-j (32-j units)
// = 33 units/block. 256 thr = 4 waves x 16 q rows. Double-buffered K/V LDS.
// 2-deep register prefetch (sets A/B, static t&1 indexing) + raw
// lgkmcnt(0)+s_barrier (no vmcnt drain): ds_write(t)'s data-dep gives a
// precise compiler vmcnt wait on loads issued at t-2 (age ~2 compute phases
// >= HBM latency). Dbuf safety: write(t+2) vs readers of compute(t) are
// separated by barrier(t+1), whose lgkmcnt(0) drains the readers' ds_reads.
__device__ __forceinline__ void load_kv(const __bf16* kb, const __bf16* vb,
                                        int tile, int rK, int sK, int dbase,
                                        int sg, bf16x8* kreg, bf16x8* vreg) {
  const __bf16* kg = kb + (size_t)(tile * 64 + rK) * 6144 + sK * 8;
#pragma unroll
  for (int kk = 0; kk < 4; ++kk) kreg[kk] = *(const bf16x8*)(kg + kk * 32);
  const __bf16* vg = vb + tile * 64 + sg * 8;
#pragma unroll
  for (int kk = 0; kk < 4; ++kk)
    vreg[kk] = *(const bf16x8*)(vg + (size_t)(dbase + kk * 32) * 2048);
}

__device__ __forceinline__ void store_kv(char* Ks, char* Vs, int rK, int sK,
                                         int dbase, int sg,
                                         const bf16x8* kreg, const bf16x8* vreg) {
#pragma unroll
  for (int kk = 0; kk < 4; ++kk)
    *(bf16x8*)(Ks + rK * 256 + ((sK * 16 + kk * 64) ^ ((rK & 7) << 4))) = kreg[kk];
#pragma unroll
  for (int kk = 0; kk < 4; ++kk) {
    int d = dbase + kk * 32;
    *(bf16x8*)(Vs + d * 128 + ((sg * 16) ^ ((d & 7) << 4))) = vreg[kk];
  }
}

__device__ __forceinline__ void attn_segment(const __bf16* __restrict__ qkv,
                                             const __bf16* __restrict__ vt,
                                             __bf16* __restrict__ aout,
                                             int b, int h, int bh,
                                             int qseg0, int nt,
                                             char* smem, int tid) {
  const int wid = tid >> 6, lane = tid & 63;
  const int g = lane >> 4, lc = lane & 15;
  const int q0w = qseg0 + wid * 16;
  const float k2e = K2E;

  bf16x8 qreg[4];
  {
    const __bf16* qp = qkv + (size_t)(b * 2048 + q0w + lc) * 6144 + h * 128 + g * 8;
#pragma unroll
    for (int c = 0; c < 4; ++c) qreg[c] = *(const bf16x8*)(qp + c * 32);
  }

  f32x4 oaccT[8];
#pragma unroll
  for (int dc = 0; dc < 8; ++dc) oaccT[dc] = f32x4{0.f, 0.f, 0.f, 0.f};
  float m_run = -1e30f, l_run = 0.f;

  const int rK = tid >> 2, sK = tid & 3;
  const int dbase = tid >> 3, sg = tid & 7;
  const __bf16* kb = qkv + (size_t)(b * 2048) * 6144 + 2048 + h * 128;
  const __bf16* vb = vt + (size_t)bh * 262144;

  bf16x8 kregA[4], vregA[4], kregB[4], vregB[4];
  load_kv(kb, vb, 0, rK, sK, dbase, sg, kregA, vregA);
  load_kv(kb, vb, (nt > 1) ? 1 : 0, rK, sK, dbase, sg, kregB, vregB);

  __syncthreads();  // segment entry: prior readers of both buffers done

  for (int t = 0; t < nt; ++t) {
    const int kv0 = t * 64;
    char* Ks = smem + (t & 1) * 16384;
    char* Vs = smem + 32768 + (t & 1) * 16384;

    if ((t & 1) == 0) {
      store_kv(Ks, Vs, rK, sK, dbase, sg, kregA, vregA);
      asm volatile("s_waitcnt lgkmcnt(0)\n\ts_barrier" ::: "memory");
      if (t + 2 < nt) load_kv(kb, vb, t + 2, rK, sK, dbase, sg, kregA, vregA);
    } else {
      store_kv(Ks, Vs, rK, sK, dbase, sg, kregB, vregB);
      asm volatile("s_waitcnt lgkmcnt(0)\n\ts_barrier" ::: "memory");
      if (t + 2 < nt) load_kv(kb, vb, t + 2, rK, sK, dbase, sg, kregB, vregB);
    }

    // S^T = K Q^T : lane holds S^T[kv = kc*16+g*4+r][q = lc]
    f32x4 sacc[4];
#pragma unroll
    for (int kc = 0; kc < 4; ++kc) sacc[kc] = f32x4{0.f, 0.f, 0.f, 0.f};
    __builtin_amdgcn_s_setprio(1);
#pragma unroll
    for (int kc = 0; kc < 4; ++kc) {
      const int kr = kc * 16 + lc;
#pragma unroll
      for (int c = 0; c < 4; ++c) {
        bf16x8 kf = *(const bf16x8*)(Ks + kr * 256 + ((c * 64 + g * 16) ^ ((kr & 7) << 4)));
        sacc[kc] = MFMA_BF16(kf, qreg[c], sacc[kc], 0, 0, 0);
      }
    }
    __builtin_amdgcn_s_setprio(0);

    // causal mask (only the diagonal tile)
    if (kv0 + 63 > q0w) {
#pragma unroll
      for (int kc = 0; kc < 4; ++kc)
#pragma unroll
        for (int r = 0; r < 4; ++r)
          if (kv0 + kc * 16 + g * 4 + r > q0w + lc) sacc[kc][r] = -1e30f;
    }

    // online softmax (lane-local per q=lc) + in-register P^T exchange
    float mx = sacc[0][0];
#pragma unroll
    for (int kc = 0; kc < 4; ++kc)
#pragma unroll
      for (int r = 0; r < 4; ++r) mx = fmaxf(mx, sacc[kc][r]);
    mx = fmaxf(mx, __shfl_xor(mx, 16));
    mx = fmaxf(mx, __shfl_xor(mx, 32));
    float mn = fmaxf(m_run, mx);
    float al = exp2f((m_run - mn) * k2e);
    m_run = mn;
    float p[4][4];
    float ls = 0.f;
#pragma unroll
    for (int kc = 0; kc < 4; ++kc)
#pragma unroll
      for (int r = 0; r < 4; ++r) {
        p[kc][r] = exp2f((sacc[kc][r] - mn) * k2e);
        ls += p[kc][r];
      }
    ls += __shfl_xor(ls, 16);
    ls += __shfl_xor(ls, 32);
    l_run = l_run * al + ls;
#pragma unroll
    for (int dc = 0; dc < 8; ++dc)
#pragma unroll
      for (int r = 0; r < 4; ++r) oaccT[dc][r] *= al;

    unsigned pk[4][2];
#pragma unroll
    for (int kc = 0; kc < 4; ++kc)
#pragma unroll
      for (int hh = 0; hh < 2; ++hh)
        pk[kc][hh] = f2bfu(p[kc][2 * hh]) | (f2bfu(p[kc][2 * hh + 1]) << 16);

    const int sA = (g & 1) * 32 + lc, sB = sA + 16;
    const bool hi = (g >> 1) != 0;
    bf16x8 brg[2];
#pragma unroll
    for (int c = 0; c < 2; ++c) {
      unsigned a0 = (unsigned)__shfl((int)pk[2 * c][0], sA);
      unsigned b0v = (unsigned)__shfl((int)pk[2 * c + 1][0], sA);
      unsigned a1 = (unsigned)__shfl((int)pk[2 * c][1], sA);
      unsigned b1v = (unsigned)__shfl((int)pk[2 * c + 1][1], sA);
      unsigned a2 = (unsigned)__shfl((int)pk[2 * c][0], sB);
      unsigned b2v = (unsigned)__shfl((int)pk[2 * c + 1][0], sB);
      unsigned a3 = (unsigned)__shfl((int)pk[2 * c][1], sB);
      unsigned b3v = (unsigned)__shfl((int)pk[2 * c + 1][1], sB);
      u32x4 wv;
      wv[0] = hi ? b0v : a0;
      wv[1] = hi ? b1v : a1;
      wv[2] = hi ? b2v : a2;
      wv[3] = hi ? b3v : a3;
      brg[c] = __builtin_bit_cast(bf16x8, wv);
    }

    // O^T += V^T P^T
    __builtin_amdgcn_s_setprio(1);
#pragma unroll
    for (int dc = 0; dc < 8; ++dc) {
      const int vr = dc * 16 + lc;
      bf16x8 vf0 = *(const bf16x8*)(Vs + vr * 128 + ((g * 16) ^ ((vr & 7) << 4)));
      bf16x8 vf1 = *(const bf16x8*)(Vs + vr * 128 + ((64 + g * 16) ^ ((vr & 7) << 4)));
      oaccT[dc] = MFMA_BF16(vf0, brg[0], oaccT[dc], 0, 0, 0);
      oaccT[dc] = MFMA_BF16(vf1, brg[1], oaccT[dc], 0, 0, 0);
    }
    __builtin_amdgcn_s_setprio(0);
  }

  {
    float inv = 1.f / l_run;
    __bf16* op = aout + (size_t)(b * 2048 + q0w + lc) * 2048 + h * 128 + g * 4;
#pragma unroll
    for (int dc = 0; dc < 8; ++dc) {
      bf16x4 o;
#pragma unroll
      for (int r = 0; r < 4; ++r) o[r] = f2bf(oaccT[dc][r] * inv);
      *(bf16x4*)(op + dc * 16) = o;
    }
  }
}

__global__ __launch_bounds__(256, 2) void flash_attn(const __bf16* __restrict__ qkv,
                                                     const __bf16* __restrict__ vt,
                                                     __bf16* __restrict__ aout) {
  __shared__ __attribute__((aligned(16))) char smem[65536];
  const int tid = threadIdx.x;
  const int j = blockIdx.x;
  const int bh = blockIdx.y, b = bh >> 4, h = bh & 15;

  attn_segment(qkv, vt, aout, b, h, bh, j * 64, j + 1, smem, tid);
  attn_segment(qkv, vt, aout, b, h, bh, (31 - j) * 64, 32 - j, smem, tid);
}

// ---------------- launch ----------------
extern "C" void kernel_launch(void* const* d_in, const int* in_sizes, int n_in,
                              void* d_out, int out_size, void* d_ws, size_t ws_size,
                              hipStream_t stream) {
  const float* x    = (const float*)d_in[0];
  const float* fcos = (const float*)d_in[1];
  const float* fsin = (const float*)d_in[2];
  const float* Wq   = (const float*)d_in[3];
  const float* Wk   = (const float*)d_in[4];
  const float* Wv   = (const float*)d_in[5];
  const float* Wo   = (const float*)d_in[6];

  char* ws = (char*)d_ws;
  __bf16* xb   = (__bf16*)(ws);               // 4096x2048
  __bf16* Wqkv = (__bf16*)(ws + 16777216);    // 6144x2048 (Wq|Wk|Wv rows)
  __bf16* Wob  = (__bf16*)(ws + 41943040);    // 2048x2048 (contiguous after Wqkv)
  __bf16* QKV  = (__bf16*)(ws + 50331648);    // 4096x6144
  __bf16* Vt   = (__bf16*)(ws + 100663296);   // (B*H) x 128 x 2048
  __bf16* aout = (__bf16*)(ws + 117440512);   // 4096x2048
  float* out = (float*)d_out;

  cvt_all<<<12288, 256, 0, stream>>>(x, Wq, Wk, Wv, Wo, xb);

  gemm128<false, true><<<dim3(24, 32), 512, 0, stream>>>(xb, Wqkv, QKV, fcos, fsin,
                                                         4096, 6144, 2048);
  transpose_v<<<dim3(64, 64, 2), dim3(32, 8), 0, stream>>>(QKV, Vt);
  flash_attn<<<dim3(16, 32), 256, 0, stream>>>(QKV, Vt, aout);
  gemm128<true, false><<<dim3(8, 32), 512, 0, stream>>>(aout, Wob, out, nullptr, nullptr,
                                                        4096, 2048, 2048);
}

// Round 17
// 268.286 us; speedup vs baseline: 1.0377x; 1.0377x over previous
//
#include <hip/hip_runtime.h>
#include <cstdint>
#include <cstddef>

typedef float f32x4 __attribute__((ext_vector_type(4)));
typedef short bf16x8 __attribute__((ext_vector_type(8)));
typedef short bf16x4 __attribute__((ext_vector_type(4)));
typedef unsigned int u32x4 __attribute__((ext_vector_type(4)));

#define LOG2E 1.4426950408889634f
#define K2E 0.12750102296293331f  /* (1/sqrt(128))*log2(e) */
#define MFMA_BF16 __builtin_amdgcn_mfma_f32_16x16x32_bf16

__device__ inline float bf2f(short s) {
  return (float)__builtin_bit_cast(__bf16, s);
}
__device__ inline short f2bf(float f) {
  return __builtin_bit_cast(short, (__bf16)f);
}
__device__ inline unsigned f2bfu(float f) {
  return (unsigned)__builtin_bit_cast(unsigned short, (__bf16)f);
}

__device__ inline void gload_lds16(const void* g, void* l) {
  __builtin_amdgcn_global_load_lds(
      (const __attribute__((address_space(1))) void*)g,
      (__attribute__((address_space(3))) void*)l, 16, 0, 0);
}

// ------- fused fp32->bf16: x (8.4M) then Wq|Wk|Wv|Wo (4x4.2M), one output --
__global__ __launch_bounds__(256) void cvt_all(const float* __restrict__ x,
                                               const float* __restrict__ w0,
                                               const float* __restrict__ w1,
                                               const float* __restrict__ w2,
                                               const float* __restrict__ w3,
                                               __bf16* __restrict__ out) {
  int i = (blockIdx.x * 256 + threadIdx.x) * 8;  // [0, 25165824)
  const float* s;
  int off;
  if (i < 8388608) {
    s = x; off = i;
  } else {
    int j = i - 8388608;
    int sel = j >> 22;  // block-uniform
    s = (sel == 0) ? w0 : (sel == 1) ? w1 : (sel == 2) ? w2 : w3;
    off = j & 4194303;
  }
  f32x4 a = *(const f32x4*)(s + off);
  f32x4 b = *(const f32x4*)(s + off + 4);
  bf16x8 r;
#pragma unroll
  for (int j = 0; j < 4; ++j) {
    r[j]     = f2bf(a[j]);
    r[j + 4] = f2bf(b[j]);
  }
  *(bf16x8*)(out + i) = r;
}

// ============ 128x256 2-phase GEMM: C = A * B^T (zero-tail grids) ============
// Triple-buffered A/B0/B1. Phase = [ds_reads; stage; counted-vmcnt; barrier;
// MFMA]. ROPE: fused rotary on the f32 acc in the epilogue (Q/K cols only;
// pair = adjacent lanes via shfl_xor(1)).
__device__ inline void stage_half(const __bf16* __restrict__ gbase, int K,
                                  int k0, char* ldsHalf, int wid, int lane) {
#pragma unroll
  for (int j = 0; j < 2; ++j) {
    int idx = (wid * 2 + j) * 64 + lane;
    int row = idx >> 3;
    int c16 = (idx & 7) ^ (row & 7);
    gload_lds16(gbase + (size_t)row * K + k0 + c16 * 8,
                ldsHalf + (wid * 2 + j) * 1024);
  }
}

__device__ inline bf16x8 lds_frag(const char* halfbase, int row, int ks, int g) {
  return *(const bf16x8*)(halfbase + row * 128 + ((((ks << 2) | g) ^ (row & 7)) << 4));
}

#define WAITV(n) asm volatile("s_waitcnt vmcnt(" #n ")" ::: "memory")

template <bool OUT_F32, bool ROPE>
__global__ __launch_bounds__(512, 1) void gemm128(const __bf16* __restrict__ A,
                                                  const __bf16* __restrict__ B,
                                                  void* __restrict__ Cv,
                                                  const float* __restrict__ fc,
                                                  const float* __restrict__ fs,
                                                  int M, int N, int K) {
  __shared__ __attribute__((aligned(128))) char lds[147456];
  const int tid = threadIdx.x, wid = tid >> 6, lane = tid & 63;
  const int g = lane >> 4, lc = lane & 15;
  const int wm = wid >> 2, wn = wid & 3;

  const int gx = gridDim.x;
  int nwg = gx * gridDim.y;
  int bid = blockIdx.y * gx + blockIdx.x;
  int cpx = nwg >> 3;
  int swz = (bid & 7) * cpx + (bid >> 3);
  const int bx = swz % gx, by = swz / gx;

  const __bf16* Ag = A + (size_t)(by * 128) * K;
  const __bf16* Bg = B + (size_t)(bx * 256) * K;
  const __bf16* Bg1 = Bg + 128 * (size_t)K;
  const int NT = K >> 6;

  f32x4 acc[2][4][2];
#pragma unroll
  for (int hb = 0; hb < 2; ++hb)
#pragma unroll
    for (int m = 0; m < 4; ++m)
#pragma unroll
      for (int n = 0; n < 2; ++n) acc[hb][m][n] = f32x4{0.f, 0.f, 0.f, 0.f};

  stage_half(Ag,  K, 0,  lds + 0,             wid, lane);
  stage_half(Bg,  K, 0,  lds + 49152,         wid, lane);
  stage_half(Bg1, K, 0,  lds + 98304,         wid, lane);
  stage_half(Ag,  K, 64, lds + 16384,         wid, lane);
  stage_half(Bg,  K, 64, lds + 49152 + 16384, wid, lane);
  stage_half(Bg1, K, 64, lds + 98304 + 16384, wid, lane);
  WAITV(8);
  __builtin_amdgcn_s_barrier();

  bf16x8 a[4][2], b0[2][2], b1[2][2];
  int sc = 0;

  for (int T = 0; T < NT; ++T) {
    char* As  = lds + sc * 16384;
    char* B0s = lds + 49152 + sc * 16384;
    char* B1s = lds + 98304 + sc * 16384;
    int s2 = sc + 2; if (s2 >= 3) s2 -= 3;
    char* As2  = lds + s2 * 16384;
    char* B0s2 = lds + 49152 + s2 * 16384;
    char* B1s2 = lds + 98304 + s2 * 16384;
    const int k2 = (T + 2) << 6;

    // ---- phase 1: C-half 0 ----
#pragma unroll
    for (int m = 0; m < 4; ++m)
#pragma unroll
      for (int ks = 0; ks < 2; ++ks)
        a[m][ks] = lds_frag(As, wm * 64 + m * 16 + lc, ks, g);
#pragma unroll
    for (int n = 0; n < 2; ++n)
#pragma unroll
      for (int ks = 0; ks < 2; ++ks)
        b0[n][ks] = lds_frag(B0s, wn * 32 + n * 16 + lc, ks, g);
    if (T + 2 < NT) {
      stage_half(Ag, K, k2, As2, wid, lane);
      stage_half(Bg, K, k2, B0s2, wid, lane);
      WAITV(10);
    } else if (T + 1 < NT) {
      WAITV(6);
    } else {
      WAITV(0);
    }
    __builtin_amdgcn_s_barrier();
    __builtin_amdgcn_s_setprio(1);
#pragma unroll
    for (int m = 0; m < 4; ++m)
#pragma unroll
      for (int n = 0; n < 2; ++n) {
        acc[0][m][n] = MFMA_BF16(a[m][0], b0[n][0], acc[0][m][n], 0, 0, 0);
        acc[0][m][n] = MFMA_BF16(a[m][1], b0[n][1], acc[0][m][n], 0, 0, 0);
      }
    __builtin_amdgcn_s_setprio(0);

    // ---- phase 2: C-half 1 ----
#pragma unroll
    for (int n = 0; n < 2; ++n)
#pragma unroll
      for (int ks = 0; ks < 2; ++ks)
        b1[n][ks] = lds_frag(B1s, wn * 32 + n * 16 + lc, ks, g);
    if (T + 2 < NT) {
      stage_half(Bg1, K, k2, B1s2, wid, lane);
      WAITV(8);
    } else if (T + 1 < NT) {
      WAITV(2);
    }
    __builtin_amdgcn_s_barrier();
    __builtin_amdgcn_s_setprio(1);
#pragma unroll
    for (int m = 0; m < 4; ++m)
#pragma unroll
      for (int n = 0; n < 2; ++n) {
        acc[1][m][n] = MFMA_BF16(a[m][0], b1[n][0], acc[1][m][n], 0, 0, 0);
        acc[1][m][n] = MFMA_BF16(a[m][1], b1[n][1], acc[1][m][n], 0, 0, 0);
      }
    __builtin_amdgcn_s_setprio(0);

    sc = (sc + 1 == 3) ? 0 : sc + 1;
  }

  // ---- fused RoPE on f32 acc (Q/K cols: bx < 16 covers cols < 4096) ----
  if (ROPE && bx < 16) {
#pragma unroll
    for (int m = 0; m < 4; ++m)
#pragma unroll
      for (int r = 0; r < 4; ++r) {
        int l = (by * 128 + wm * 64 + m * 16 + g * 4 + r) & 2047;
#pragma unroll
        for (int n = 0; n < 2; ++n) {
          int i0 = (wn * 32 + n * 16 + lc) >> 1;
          float c = fc[l * 64 + i0];
          float s = fs[l * 64 + i0];
#pragma unroll
          for (int hb = 0; hb < 2; ++hb) {
            float v = acc[hb][m][n][r];
            float pv = __shfl_xor(v, 1);
            acc[hb][m][n][r] = (lc & 1) ? (pv * s + v * c) : (v * c - pv * s);
          }
        }
      }
  }

  // epilogue
#pragma unroll
  for (int hb = 0; hb < 2; ++hb)
#pragma unroll
    for (int m = 0; m < 4; ++m)
#pragma unroll
      for (int n = 0; n < 2; ++n)
#pragma unroll
        for (int r = 0; r < 4; ++r) {
          int rr = by * 128 + wm * 64 + m * 16 + g * 4 + r;
          int cc = bx * 256 + hb * 128 + wn * 32 + n * 16 + lc;
          if (OUT_F32)
            ((float*)Cv)[(size_t)rr * N + cc] = acc[hb][m][n][r];
          else
            ((__bf16*)Cv)[(size_t)rr * N + cc] = (__bf16)acc[hb][m][n][r];
        }
}

// ---------------- V transpose: (b,l,h,d) -> (b,h,d,l) ----------------
__global__ void transpose_v(const __bf16* __restrict__ qkv, __bf16* __restrict__ vt) {
  __shared__ __bf16 tile[32][33];
  const int b = blockIdx.z;
  const int l0 = blockIdx.x * 32, c0 = blockIdx.y * 32;
  for (int i = threadIdx.y; i < 32; i += 8)
    tile[i][threadIdx.x] = qkv[(size_t)(b * 2048 + l0 + i) * 6144 + 4096 + c0 + threadIdx.x];
  __syncthreads();
  for (int i = threadIdx.y; i < 32; i += 8)
    vt[(size_t)b * 4194304 + (size_t)(c0 + i) * 2048 + l0 + threadIdx.x] = tile[threadIdx.x][i];
}

// ---------------- causal flash attention, uniform paired q-tiles ----------
// 32 q-tiles of 64 rows. Block j in [0,16) runs q-tile j (j+1 kv tiles) then
// q-tile 31-j (32-j kv tiles): 33 kv-tile iterations for EVERY block -> exact
// load balance. 256 threads = 4 waves x 16 q rows.
// Double-buffered K/V LDS (64KB): ONE barrier per kv-unit. (R16's deeper
// prefetch + raw lgkm-only barrier regressed ~10us: extra VGPR pressure +
// asm memory clobber splitting scheduling regions. Keep this form.)
__device__ __forceinline__ void attn_segment(const __bf16* __restrict__ qkv,
                                             const __bf16* __restrict__ vt,
                                             __bf16* __restrict__ aout,
                                             int b, int h, int bh,
                                             int qseg0, int nt,
                                             char* smem, int tid) {
  const int wid = tid >> 6, lane = tid & 63;
  const int g = lane >> 4, lc = lane & 15;
  const int q0w = qseg0 + wid * 16;
  const float k2e = K2E;

  bf16x8 qreg[4];
  {
    const __bf16* qp = qkv + (size_t)(b * 2048 + q0w + lc) * 6144 + h * 128 + g * 8;
#pragma unroll
    for (int c = 0; c < 4; ++c) qreg[c] = *(const bf16x8*)(qp + c * 32);
  }

  f32x4 oaccT[8];
#pragma unroll
  for (int dc = 0; dc < 8; ++dc) oaccT[dc] = f32x4{0.f, 0.f, 0.f, 0.f};
  float m_run = -1e30f, l_run = 0.f;

  const int rK = tid >> 2, sK = tid & 3;
  const int dbase = tid >> 3, sg = tid & 7;
  const __bf16* kb = qkv + (size_t)(b * 2048) * 6144 + 2048 + h * 128;
  const __bf16* vb = vt + (size_t)bh * 262144;

  bf16x8 kreg[4], vreg[4];
  {
    const __bf16* kg = kb + (size_t)rK * 6144 + sK * 8;
#pragma unroll
    for (int kk = 0; kk < 4; ++kk) kreg[kk] = *(const bf16x8*)(kg + kk * 32);
    const __bf16* vg = vb + sg * 8;
#pragma unroll
    for (int kk = 0; kk < 4; ++kk)
      vreg[kk] = *(const bf16x8*)(vg + (size_t)(dbase + kk * 32) * 2048);
  }

  __syncthreads();  // segment entry: prior readers of both buffers done

  for (int t = 0; t < nt; ++t) {
    const int kv0 = t * 64;
    char* Ks = smem + (t & 1) * 16384;
    char* Vs = smem + 32768 + (t & 1) * 16384;

    // write tile t (in regs) to buf[t&1]
#pragma unroll
    for (int kk = 0; kk < 4; ++kk)
      *(bf16x8*)(Ks + rK * 256 + ((sK * 16 + kk * 64) ^ ((rK & 7) << 4))) = kreg[kk];
#pragma unroll
    for (int kk = 0; kk < 4; ++kk) {
      int d = dbase + kk * 32;
      *(bf16x8*)(Vs + d * 128 + ((sg * 16) ^ ((d & 7) << 4))) = vreg[kk];
    }
    __syncthreads();  // tile t visible; single barrier per unit

    // issue next-tile global loads (overlap with compute below)
    if (t + 1 < nt) {
      const __bf16* kg = kb + (size_t)(kv0 + 64 + rK) * 6144 + sK * 8;
#pragma unroll
      for (int kk = 0; kk < 4; ++kk) kreg[kk] = *(const bf16x8*)(kg + kk * 32);
      const __bf16* vg = vb + kv0 + 64 + sg * 8;
#pragma unroll
      for (int kk = 0; kk < 4; ++kk)
        vreg[kk] = *(const bf16x8*)(vg + (size_t)(dbase + kk * 32) * 2048);
    }

    // S^T = K Q^T : lane holds S^T[kv = kc*16+g*4+r][q = lc]
    f32x4 sacc[4];
#pragma unroll
    for (int kc = 0; kc < 4; ++kc) sacc[kc] = f32x4{0.f, 0.f, 0.f, 0.f};
#pragma unroll
    for (int kc = 0; kc < 4; ++kc) {
      const int kr = kc * 16 + lc;
#pragma unroll
      for (int c = 0; c < 4; ++c) {
        bf16x8 kf = *(const bf16x8*)(Ks + kr * 256 + ((c * 64 + g * 16) ^ ((kr & 7) << 4)));
        sacc[kc] = MFMA_BF16(kf, qreg[c], sacc[kc], 0, 0, 0);
      }
    }

    // causal mask (only the diagonal tile)
    if (kv0 + 63 > q0w) {
#pragma unroll
      for (int kc = 0; kc < 4; ++kc)
#pragma unroll
        for (int r = 0; r < 4; ++r)
          if (kv0 + kc * 16 + g * 4 + r > q0w + lc) sacc[kc][r] = -1e30f;
    }

    // online softmax (lane-local per q=lc) + in-register P^T exchange
    float mx = sacc[0][0];
#pragma unroll
    for (int kc = 0; kc < 4; ++kc)
#pragma unroll
      for (int r = 0; r < 4; ++r) mx = fmaxf(mx, sacc[kc][r]);
    mx = fmaxf(mx, __shfl_xor(mx, 16));
    mx = fmaxf(mx, __shfl_xor(mx, 32));
    float mn = fmaxf(m_run, mx);
    float al = exp2f((m_run - mn) * k2e);
    m_run = mn;
    float p[4][4];
    float ls = 0.f;
#pragma unroll
    for (int kc = 0; kc < 4; ++kc)
#pragma unroll
      for (int r = 0; r < 4; ++r) {
        p[kc][r] = exp2f((sacc[kc][r] - mn) * k2e);
        ls += p[kc][r];
      }
    ls += __shfl_xor(ls, 16);
    ls += __shfl_xor(ls, 32);
    l_run = l_run * al + ls;
#pragma unroll
    for (int dc = 0; dc < 8; ++dc)
#pragma unroll
      for (int r = 0; r < 4; ++r) oaccT[dc][r] *= al;

    unsigned pk[4][2];
#pragma unroll
    for (int kc = 0; kc < 4; ++kc)
#pragma unroll
      for (int hh = 0; hh < 2; ++hh)
        pk[kc][hh] = f2bfu(p[kc][2 * hh]) | (f2bfu(p[kc][2 * hh + 1]) << 16);

    const int sA = (g & 1) * 32 + lc, sB = sA + 16;
    const bool hi = (g >> 1) != 0;
    bf16x8 brg[2];
#pragma unroll
    for (int c = 0; c < 2; ++c) {
      unsigned a0 = (unsigned)__shfl((int)pk[2 * c][0], sA);
      unsigned b0v = (unsigned)__shfl((int)pk[2 * c + 1][0], sA);
      unsigned a1 = (unsigned)__shfl((int)pk[2 * c][1], sA);
      unsigned b1v = (unsigned)__shfl((int)pk[2 * c + 1][1], sA);
      unsigned a2 = (unsigned)__shfl((int)pk[2 * c][0], sB);
      unsigned b2v = (unsigned)__shfl((int)pk[2 * c + 1][0], sB);
      unsigned a3 = (unsigned)__shfl((int)pk[2 * c][1], sB);
      unsigned b3v = (unsigned)__shfl((int)pk[2 * c + 1][1], sB);
      u32x4 wv;
      wv[0] = hi ? b0v : a0;
      wv[1] = hi ? b1v : a1;
      wv[2] = hi ? b2v : a2;
      wv[3] = hi ? b3v : a3;
      brg[c] = __builtin_bit_cast(bf16x8, wv);
    }

    // O^T += V^T P^T
#pragma unroll
    for (int dc = 0; dc < 8; ++dc) {
      const int vr = dc * 16 + lc;
      bf16x8 vf0 = *(const bf16x8*)(Vs + vr * 128 + ((g * 16) ^ ((vr & 7) << 4)));
      bf16x8 vf1 = *(const bf16x8*)(Vs + vr * 128 + ((64 + g * 16) ^ ((vr & 7) << 4)));
      oaccT[dc] = MFMA_BF16(vf0, brg[0], oaccT[dc], 0, 0, 0);
      oaccT[dc] = MFMA_BF16(vf1, brg[1], oaccT[dc], 0, 0, 0);
    }
  }

  {
    float inv = 1.f / l_run;
    __bf16* op = aout + (size_t)(b * 2048 + q0w + lc) * 2048 + h * 128 + g * 4;
#pragma unroll
    for (int dc = 0; dc < 8; ++dc) {
      bf16x4 o;
#pragma unroll
      for (int r = 0; r < 4; ++r) o[r] = f2bf(oaccT[dc][r] * inv);
      *(bf16x4*)(op + dc * 16) = o;
    }
  }
}

__global__ __launch_bounds__(256, 2) void flash_attn(const __bf16* __restrict__ qkv,
                                                     const __bf16* __restrict__ vt,
                                                     __bf16* __restrict__ aout) {
  __shared__ __attribute__((aligned(16))) char smem[65536];
  const int tid = threadIdx.x;
  const int j = blockIdx.x;
  const int bh = blockIdx.y, b = bh >> 4, h = bh & 15;

  attn_segment(qkv, vt, aout, b, h, bh, j * 64, j + 1, smem, tid);
  attn_segment(qkv, vt, aout, b, h, bh, (31 - j) * 64, 32 - j, smem, tid);
}

// ---------------- launch ----------------
extern "C" void kernel_launch(void* const* d_in, const int* in_sizes, int n_in,
                              void* d_out, int out_size, void* d_ws, size_t ws_size,
                              hipStream_t stream) {
  const float* x    = (const float*)d_in[0];
  const float* fcos = (const float*)d_in[1];
  const float* fsin = (const float*)d_in[2];
  const float* Wq   = (const float*)d_in[3];
  const float* Wk   = (const float*)d_in[4];
  const float* Wv   = (const float*)d_in[5];
  const float* Wo   = (const float*)d_in[6];

  char* ws = (char*)d_ws;
  __bf16* xb   = (__bf16*)(ws);               // 4096x2048
  __bf16* Wqkv = (__bf16*)(ws + 16777216);    // 6144x2048 (Wq|Wk|Wv rows)
  __bf16* Wob  = (__bf16*)(ws + 41943040);    // 2048x2048 (contiguous after Wqkv)
  __bf16* QKV  = (__bf16*)(ws + 50331648);    // 4096x6144
  __bf16* Vt   = (__bf16*)(ws + 100663296);   // (B*H) x 128 x 2048
  __bf16* aout = (__bf16*)(ws + 117440512);   // 4096x2048
  float* out = (float*)d_out;

  cvt_all<<<12288, 256, 0, stream>>>(x, Wq, Wk, Wv, Wo, xb);

  gemm128<false, true><<<dim3(24, 32), 512, 0, stream>>>(xb, Wqkv, QKV, fcos, fsin,
                                                         4096, 6144, 2048);
  transpose_v<<<dim3(64, 64, 2), dim3(32, 8), 0, stream>>>(QKV, Vt);
  flash_attn<<<dim3(16, 32), 256, 0, stream>>>(QKV, Vt, aout);
  gemm128<true, false><<<dim3(8, 32), 512, 0, stream>>>(aout, Wob, out, nullptr, nullptr,
                                                        4096, 2048, 2048);
}

// Round 18
// 259.132 us; speedup vs baseline: 1.0744x; 1.0353x over previous
//
#include <hip/hip_runtime.h>
#include <cstdint>
#include <cstddef>

typedef float f32x4 __attribute__((ext_vector_type(4)));
typedef short bf16x8 __attribute__((ext_vector_type(8)));
typedef short bf16x4 __attribute__((ext_vector_type(4)));
typedef unsigned int u32x4 __attribute__((ext_vector_type(4)));

#define LOG2E 1.4426950408889634f
#define K2E 0.12750102296293331f  /* (1/sqrt(128))*log2(e) */
#define MFMA_BF16 __builtin_amdgcn_mfma_f32_16x16x32_bf16

__device__ inline float bf2f(short s) {
  return (float)__builtin_bit_cast(__bf16, s);
}
__device__ inline short f2bf(float f) {
  return __builtin_bit_cast(short, (__bf16)f);
}
__device__ inline unsigned f2bfu(float f) {
  return (unsigned)__builtin_bit_cast(unsigned short, (__bf16)f);
}

__device__ inline void gload_lds16(const void* g, void* l) {
  __builtin_amdgcn_global_load_lds(
      (const __attribute__((address_space(1))) void*)g,
      (__attribute__((address_space(3))) void*)l, 16, 0, 0);
}

// ------- fused fp32->bf16: x (8.4M) then Wq|Wk|Wv|Wo (4x4.2M), one output --
__global__ __launch_bounds__(256) void cvt_all(const float* __restrict__ x,
                                               const float* __restrict__ w0,
                                               const float* __restrict__ w1,
                                               const float* __restrict__ w2,
                                               const float* __restrict__ w3,
                                               __bf16* __restrict__ out) {
  int i = (blockIdx.x * 256 + threadIdx.x) * 8;  // [0, 25165824)
  const float* s;
  int off;
  if (i < 8388608) {
    s = x; off = i;
  } else {
    int j = i - 8388608;
    int sel = j >> 22;  // block-uniform
    s = (sel == 0) ? w0 : (sel == 1) ? w1 : (sel == 2) ? w2 : w3;
    off = j & 4194303;
  }
  f32x4 a = *(const f32x4*)(s + off);
  f32x4 b = *(const f32x4*)(s + off + 4);
  bf16x8 r;
#pragma unroll
  for (int j = 0; j < 4; ++j) {
    r[j]     = f2bf(a[j]);
    r[j + 4] = f2bf(b[j]);
  }
  *(bf16x8*)(out + i) = r;
}

// ============ 128x256 2-phase GEMM: C = A * B^T (zero-tail grids) ============
// Triple-buffered A/B0/B1. Phase = [ds_reads; stage; counted-vmcnt; barrier;
// MFMA]. ROPE: fused rotary on the f32 acc in the epilogue.
// RECT: QKV-grid (24x32, 3 rounds of 256) L2-locality swizzle — each XCD's
// per-round 32 blocks form a 4bx x 8by rectangle (B-panel fetch/XCD-round:
// 24MB -> 8MB). Out-proj keeps the generic bijective XCD swizzle.
__device__ inline void stage_half(const __bf16* __restrict__ gbase, int K,
                                  int k0, char* ldsHalf, int wid, int lane) {
#pragma unroll
  for (int j = 0; j < 2; ++j) {
    int idx = (wid * 2 + j) * 64 + lane;
    int row = idx >> 3;
    int c16 = (idx & 7) ^ (row & 7);
    gload_lds16(gbase + (size_t)row * K + k0 + c16 * 8,
                ldsHalf + (wid * 2 + j) * 1024);
  }
}

__device__ inline bf16x8 lds_frag(const char* halfbase, int row, int ks, int g) {
  return *(const bf16x8*)(halfbase + row * 128 + ((((ks << 2) | g) ^ (row & 7)) << 4));
}

#define WAITV(n) asm volatile("s_waitcnt vmcnt(" #n ")" ::: "memory")

template <bool OUT_F32, bool ROPE, bool RECT>
__global__ __launch_bounds__(512, 1) void gemm128(const __bf16* __restrict__ A,
                                                  const __bf16* __restrict__ B,
                                                  void* __restrict__ Cv,
                                                  const float* __restrict__ fc,
                                                  const float* __restrict__ fs,
                                                  int M, int N, int K) {
  __shared__ __attribute__((aligned(128))) char lds[147456];
  const int tid = threadIdx.x, wid = tid >> 6, lane = tid & 63;
  const int g = lane >> 4, lc = lane & 15;
  const int wm = wid >> 2, wn = wid & 3;

  const int gx = gridDim.x;
  int nwg = gx * gridDim.y;
  int bid = blockIdx.y * gx + blockIdx.x;
  int bx, by;
  if (RECT) {
    // 24x32 grid, 768 blocks: round k (0..2), XCD x (bid&7), slot j (0..31).
    // rect = k*8+x -> 4bx x 8by rectangle; bijective onto the full grid.
    int k = bid >> 8;
    int x = bid & 7;
    int j = (bid >> 3) & 31;
    int rect = k * 8 + x;
    bx = (rect % 6) * 4 + (j & 3);
    by = (rect / 6) * 8 + (j >> 2);
  } else {
    int cpx = nwg >> 3;
    int swz = (bid & 7) * cpx + (bid >> 3);
    bx = swz % gx;
    by = swz / gx;
  }

  const __bf16* Ag = A + (size_t)(by * 128) * K;
  const __bf16* Bg = B + (size_t)(bx * 256) * K;
  const __bf16* Bg1 = Bg + 128 * (size_t)K;
  const int NT = K >> 6;

  f32x4 acc[2][4][2];
#pragma unroll
  for (int hb = 0; hb < 2; ++hb)
#pragma unroll
    for (int m = 0; m < 4; ++m)
#pragma unroll
      for (int n = 0; n < 2; ++n) acc[hb][m][n] = f32x4{0.f, 0.f, 0.f, 0.f};

  stage_half(Ag,  K, 0,  lds + 0,             wid, lane);
  stage_half(Bg,  K, 0,  lds + 49152,         wid, lane);
  stage_half(Bg1, K, 0,  lds + 98304,         wid, lane);
  stage_half(Ag,  K, 64, lds + 16384,         wid, lane);
  stage_half(Bg,  K, 64, lds + 49152 + 16384, wid, lane);
  stage_half(Bg1, K, 64, lds + 98304 + 16384, wid, lane);
  WAITV(8);
  __builtin_amdgcn_s_barrier();

  bf16x8 a[4][2], b0[2][2], b1[2][2];
  int sc = 0;

  for (int T = 0; T < NT; ++T) {
    char* As  = lds + sc * 16384;
    char* B0s = lds + 49152 + sc * 16384;
    char* B1s = lds + 98304 + sc * 16384;
    int s2 = sc + 2; if (s2 >= 3) s2 -= 3;
    char* As2  = lds + s2 * 16384;
    char* B0s2 = lds + 49152 + s2 * 16384;
    char* B1s2 = lds + 98304 + s2 * 16384;
    const int k2 = (T + 2) << 6;

    // ---- phase 1: C-half 0 ----
#pragma unroll
    for (int m = 0; m < 4; ++m)
#pragma unroll
      for (int ks = 0; ks < 2; ++ks)
        a[m][ks] = lds_frag(As, wm * 64 + m * 16 + lc, ks, g);
#pragma unroll
    for (int n = 0; n < 2; ++n)
#pragma unroll
      for (int ks = 0; ks < 2; ++ks)
        b0[n][ks] = lds_frag(B0s, wn * 32 + n * 16 + lc, ks, g);
    if (T + 2 < NT) {
      stage_half(Ag, K, k2, As2, wid, lane);
      stage_half(Bg, K, k2, B0s2, wid, lane);
      WAITV(10);
    } else if (T + 1 < NT) {
      WAITV(6);
    } else {
      WAITV(0);
    }
    __builtin_amdgcn_s_barrier();
    __builtin_amdgcn_s_setprio(1);
#pragma unroll
    for (int m = 0; m < 4; ++m)
#pragma unroll
      for (int n = 0; n < 2; ++n) {
        acc[0][m][n] = MFMA_BF16(a[m][0], b0[n][0], acc[0][m][n], 0, 0, 0);
        acc[0][m][n] = MFMA_BF16(a[m][1], b0[n][1], acc[0][m][n], 0, 0, 0);
      }
    __builtin_amdgcn_s_setprio(0);

    // ---- phase 2: C-half 1 ----
#pragma unroll
    for (int n = 0; n < 2; ++n)
#pragma unroll
      for (int ks = 0; ks < 2; ++ks)
        b1[n][ks] = lds_frag(B1s, wn * 32 + n * 16 + lc, ks, g);
    if (T + 2 < NT) {
      stage_half(Bg1, K, k2, B1s2, wid, lane);
      WAITV(8);
    } else if (T + 1 < NT) {
      WAITV(2);
    }
    __builtin_amdgcn_s_barrier();
    __builtin_amdgcn_s_setprio(1);
#pragma unroll
    for (int m = 0; m < 4; ++m)
#pragma unroll
      for (int n = 0; n < 2; ++n) {
        acc[1][m][n] = MFMA_BF16(a[m][0], b1[n][0], acc[1][m][n], 0, 0, 0);
        acc[1][m][n] = MFMA_BF16(a[m][1], b1[n][1], acc[1][m][n], 0, 0, 0);
      }
    __builtin_amdgcn_s_setprio(0);

    sc = (sc + 1 == 3) ? 0 : sc + 1;
  }

  // ---- fused RoPE on f32 acc (Q/K cols: bx < 16 covers cols < 4096) ----
  if (ROPE && bx < 16) {
#pragma unroll
    for (int m = 0; m < 4; ++m)
#pragma unroll
      for (int r = 0; r < 4; ++r) {
        int l = (by * 128 + wm * 64 + m * 16 + g * 4 + r) & 2047;
#pragma unroll
        for (int n = 0; n < 2; ++n) {
          int i0 = (wn * 32 + n * 16 + lc) >> 1;
          float c = fc[l * 64 + i0];
          float s = fs[l * 64 + i0];
#pragma unroll
          for (int hb = 0; hb < 2; ++hb) {
            float v = acc[hb][m][n][r];
            float pv = __shfl_xor(v, 1);
            acc[hb][m][n][r] = (lc & 1) ? (pv * s + v * c) : (v * c - pv * s);
          }
        }
      }
  }

  // epilogue
#pragma unroll
  for (int hb = 0; hb < 2; ++hb)
#pragma unroll
    for (int m = 0; m < 4; ++m)
#pragma unroll
      for (int n = 0; n < 2; ++n)
#pragma unroll
        for (int r = 0; r < 4; ++r) {
          int rr = by * 128 + wm * 64 + m * 16 + g * 4 + r;
          int cc = bx * 256 + hb * 128 + wn * 32 + n * 16 + lc;
          if (OUT_F32)
            ((float*)Cv)[(size_t)rr * N + cc] = acc[hb][m][n][r];
          else
            ((__bf16*)Cv)[(size_t)rr * N + cc] = (__bf16)acc[hb][m][n][r];
        }
}

// ---------------- V transpose: (b,l,h,d) -> (b,h,d,l) ----------------
__global__ void transpose_v(const __bf16* __restrict__ qkv, __bf16* __restrict__ vt) {
  __shared__ __bf16 tile[32][33];
  const int b = blockIdx.z;
  const int l0 = blockIdx.x * 32, c0 = blockIdx.y * 32;
  for (int i = threadIdx.y; i < 32; i += 8)
    tile[i][threadIdx.x] = qkv[(size_t)(b * 2048 + l0 + i) * 6144 + 4096 + c0 + threadIdx.x];
  __syncthreads();
  for (int i = threadIdx.y; i < 32; i += 8)
    vt[(size_t)b * 4194304 + (size_t)(c0 + i) * 2048 + l0 + threadIdx.x] = tile[threadIdx.x][i];
}

// ---------------- causal flash attention, uniform paired q-tiles ----------
// 32 q-tiles of 64 rows. Block j in [0,16) runs q-tile j (j+1 kv tiles) then
// q-tile 31-j (32-j kv tiles): 33 kv-tile iterations for EVERY block -> exact
// load balance. 256 threads = 4 waves x 16 q rows. Double-buffered K/V LDS,
// one __syncthreads per kv-unit. (R16's deeper prefetch regressed; keep.)
__device__ __forceinline__ void attn_segment(const __bf16* __restrict__ qkv,
                                             const __bf16* __restrict__ vt,
                                             __bf16* __restrict__ aout,
                                             int b, int h, int bh,
                                             int qseg0, int nt,
                                             char* smem, int tid) {
  const int wid = tid >> 6, lane = tid & 63;
  const int g = lane >> 4, lc = lane & 15;
  const int q0w = qseg0 + wid * 16;
  const float k2e = K2E;

  bf16x8 qreg[4];
  {
    const __bf16* qp = qkv + (size_t)(b * 2048 + q0w + lc) * 6144 + h * 128 + g * 8;
#pragma unroll
    for (int c = 0; c < 4; ++c) qreg[c] = *(const bf16x8*)(qp + c * 32);
  }

  f32x4 oaccT[8];
#pragma unroll
  for (int dc = 0; dc < 8; ++dc) oaccT[dc] = f32x4{0.f, 0.f, 0.f, 0.f};
  float m_run = -1e30f, l_run = 0.f;

  const int rK = tid >> 2, sK = tid & 3;
  const int dbase = tid >> 3, sg = tid & 7;
  const __bf16* kb = qkv + (size_t)(b * 2048) * 6144 + 2048 + h * 128;
  const __bf16* vb = vt + (size_t)bh * 262144;

  bf16x8 kreg[4], vreg[4];
  {
    const __bf16* kg = kb + (size_t)rK * 6144 + sK * 8;
#pragma unroll
    for (int kk = 0; kk < 4; ++kk) kreg[kk] = *(const bf16x8*)(kg + kk * 32);
    const __bf16* vg = vb + sg * 8;
#pragma unroll
    for (int kk = 0; kk < 4; ++kk)
      vreg[kk] = *(const bf16x8*)(vg + (size_t)(dbase + kk * 32) * 2048);
  }

  __syncthreads();  // segment entry: prior readers of both buffers done

  for (int t = 0; t < nt; ++t) {
    const int kv0 = t * 64;
    char* Ks = smem + (t & 1) * 16384;
    char* Vs = smem + 32768 + (t & 1) * 16384;

    // write tile t (in regs) to buf[t&1]
#pragma unroll
    for (int kk = 0; kk < 4; ++kk)
      *(bf16x8*)(Ks + rK * 256 + ((sK * 16 + kk * 64) ^ ((rK & 7) << 4))) = kreg[kk];
#pragma unroll
    for (int kk = 0; kk < 4; ++kk) {
      int d = dbase + kk * 32;
      *(bf16x8*)(Vs + d * 128 + ((sg * 16) ^ ((d & 7) << 4))) = vreg[kk];
    }
    __syncthreads();  // tile t visible; single barrier per unit

    // issue next-tile global loads (overlap with compute below)
    if (t + 1 < nt) {
      const __bf16* kg = kb + (size_t)(kv0 + 64 + rK) * 6144 + sK * 8;
#pragma unroll
      for (int kk = 0; kk < 4; ++kk) kreg[kk] = *(const bf16x8*)(kg + kk * 32);
      const __bf16* vg = vb + kv0 + 64 + sg * 8;
#pragma unroll
      for (int kk = 0; kk < 4; ++kk)
        vreg[kk] = *(const bf16x8*)(vg + (size_t)(dbase + kk * 32) * 2048);
    }

    // S^T = K Q^T : lane holds S^T[kv = kc*16+g*4+r][q = lc]
    f32x4 sacc[4];
#pragma unroll
    for (int kc = 0; kc < 4; ++kc) sacc[kc] = f32x4{0.f, 0.f, 0.f, 0.f};
#pragma unroll
    for (int kc = 0; kc < 4; ++kc) {
      const int kr = kc * 16 + lc;
#pragma unroll
      for (int c = 0; c < 4; ++c) {
        bf16x8 kf = *(const bf16x8*)(Ks + kr * 256 + ((c * 64 + g * 16) ^ ((kr & 7) << 4)));
        sacc[kc] = MFMA_BF16(kf, qreg[c], sacc[kc], 0, 0, 0);
      }
    }

    // causal mask (only the diagonal tile)
    if (kv0 + 63 > q0w) {
#pragma unroll
      for (int kc = 0; kc < 4; ++kc)
#pragma unroll
        for (int r = 0; r < 4; ++r)
          if (kv0 + kc * 16 + g * 4 + r > q0w + lc) sacc[kc][r] = -1e30f;
    }

    // online softmax (lane-local per q=lc) + in-register P^T exchange
    float mx = sacc[0][0];
#pragma unroll
    for (int kc = 0; kc < 4; ++kc)
#pragma unroll
      for (int r = 0; r < 4; ++r) mx = fmaxf(mx, sacc[kc][r]);
    mx = fmaxf(mx, __shfl_xor(mx, 16));
    mx = fmaxf(mx, __shfl_xor(mx, 32));
    float mn = fmaxf(m_run, mx);
    float al = exp2f((m_run - mn) * k2e);
    m_run = mn;
    float p[4][4];
    float ls = 0.f;
#pragma unroll
    for (int kc = 0; kc < 4; ++kc)
#pragma unroll
      for (int r = 0; r < 4; ++r) {
        p[kc][r] = exp2f((sacc[kc][r] - mn) * k2e);
        ls += p[kc][r];
      }
    ls += __shfl_xor(ls, 16);
    ls += __shfl_xor(ls, 32);
    l_run = l_run * al + ls;
#pragma unroll
    for (int dc = 0; dc < 8; ++dc)
#pragma unroll
      for (int r = 0; r < 4; ++r) oaccT[dc][r] *= al;

    unsigned pk[4][2];
#pragma unroll
    for (int kc = 0; kc < 4; ++kc)
#pragma unroll
      for (int hh = 0; hh < 2; ++hh)
        pk[kc][hh] = f2bfu(p[kc][2 * hh]) | (f2bfu(p[kc][2 * hh + 1]) << 16);

    const int sA = (g & 1) * 32 + lc, sB = sA + 16;
    const bool hi = (g >> 1) != 0;
    bf16x8 brg[2];
#pragma unroll
    for (int c = 0; c < 2; ++c) {
      unsigned a0 = (unsigned)__shfl((int)pk[2 * c][0], sA);
      unsigned b0v = (unsigned)__shfl((int)pk[2 * c + 1][0], sA);
      unsigned a1 = (unsigned)__shfl((int)pk[2 * c][1], sA);
      unsigned b1v = (unsigned)__shfl((int)pk[2 * c + 1][1], sA);
      unsigned a2 = (unsigned)__shfl((int)pk[2 * c][0], sB);
      unsigned b2v = (unsigned)__shfl((int)pk[2 * c + 1][0], sB);
      unsigned a3 = (unsigned)__shfl((int)pk[2 * c][1], sB);
      unsigned b3v = (unsigned)__shfl((int)pk[2 * c + 1][1], sB);
      u32x4 wv;
      wv[0] = hi ? b0v : a0;
      wv[1] = hi ? b1v : a1;
      wv[2] = hi ? b2v : a2;
      wv[3] = hi ? b3v : a3;
      brg[c] = __builtin_bit_cast(bf16x8, wv);
    }

    // O^T += V^T P^T
#pragma unroll
    for (int dc = 0; dc < 8; ++dc) {
      const int vr = dc * 16 + lc;
      bf16x8 vf0 = *(const bf16x8*)(Vs + vr * 128 + ((g * 16) ^ ((vr & 7) << 4)));
      bf16x8 vf1 = *(const bf16x8*)(Vs + vr * 128 + ((64 + g * 16) ^ ((vr & 7) << 4)));
      oaccT[dc] = MFMA_BF16(vf0, brg[0], oaccT[dc], 0, 0, 0);
      oaccT[dc] = MFMA_BF16(vf1, brg[1], oaccT[dc], 0, 0, 0);
    }
  }

  {
    float inv = 1.f / l_run;
    __bf16* op = aout + (size_t)(b * 2048 + q0w + lc) * 2048 + h * 128 + g * 4;
#pragma unroll
    for (int dc = 0; dc < 8; ++dc) {
      bf16x4 o;
#pragma unroll
      for (int r = 0; r < 4; ++r) o[r] = f2bf(oaccT[dc][r] * inv);
      *(bf16x4*)(op + dc * 16) = o;
    }
  }
}

__global__ __launch_bounds__(256, 2) void flash_attn(const __bf16* __restrict__ qkv,
                                                     const __bf16* __restrict__ vt,
                                                     __bf16* __restrict__ aout) {
  __shared__ __attribute__((aligned(16))) char smem[65536];
  const int tid = threadIdx.x;
  const int j = blockIdx.x;
  const int bh = blockIdx.y, b = bh >> 4, h = bh & 15;

  attn_segment(qkv, vt, aout, b, h, bh, j * 64, j + 1, smem, tid);
  attn_segment(qkv, vt, aout, b, h, bh, (31 - j) * 64, 32 - j, smem, tid);
}

// ---------------- launch ----------------
extern "C" void kernel_launch(void* const* d_in, const int* in_sizes, int n_in,
                              void* d_out, int out_size, void* d_ws, size_t ws_size,
                              hipStream_t stream) {
  const float* x    = (const float*)d_in[0];
  const float* fcos = (const float*)d_in[1];
  const float* fsin = (const float*)d_in[2];
  const float* Wq   = (const float*)d_in[3];
  const float* Wk   = (const float*)d_in[4];
  const float* Wv   = (const float*)d_in[5];
  const float* Wo   = (const float*)d_in[6];

  char* ws = (char*)d_ws;
  __bf16* xb   = (__bf16*)(ws);               // 4096x2048
  __bf16* Wqkv = (__bf16*)(ws + 16777216);    // 6144x2048 (Wq|Wk|Wv rows)
  __bf16* Wob  = (__bf16*)(ws + 41943040);    // 2048x2048 (contiguous after Wqkv)
  __bf16* QKV  = (__bf16*)(ws + 50331648);    // 4096x6144
  __bf16* Vt   = (__bf16*)(ws + 100663296);   // (B*H) x 128 x 2048
  __bf16* aout = (__bf16*)(ws + 117440512);   // 4096x2048
  float* out = (float*)d_out;

  cvt_all<<<12288, 256, 0, stream>>>(x, Wq, Wk, Wv, Wo, xb);

  gemm128<false, true, true><<<dim3(24, 32), 512, 0, stream>>>(xb, Wqkv, QKV, fcos, fsin,
                                                               4096, 6144, 2048);
  transpose_v<<<dim3(64, 64, 2), dim3(32, 8), 0, stream>>>(QKV, Vt);
  flash_attn<<<dim3(16, 32), 256, 0, stream>>>(QKV, Vt, aout);
  gemm128<true, false, false><<<dim3(8, 32), 512, 0, stream>>>(aout, Wob, out, nullptr, nullptr,
                                                               4096, 2048, 2048);
}